// Round 3
// baseline (69.139 us; speedup 1.0000x reference)
//
#include <hip/hip_runtime.h>

// BilateralFilter, fp32, N=8 images 512x512, 3x3, sigma=0.8 (space/density/color).
// One wave per image row: 64 lanes x 8 px. Window edges via __shfl (no scalar
// edge loads). Center-tap exps folded (==1); horizontal pair weights shared.
// out = Stc / (St + 9e-7*Swd*Swc)   [1e-7*Sum(cp) term provably negligible]

constexpr int HH = 512;
constexpr int WW = 512;
constexpr int HW = HH * WW;

#define KEXP (-1.1271055f)            // -(1/(2*0.8^2)) * log2(e)
#define E2(x) __builtin_amdgcn_exp2f(x)

#define WS0f 0.2724967f               // normalized spatial gaussian d2=0
#define WS1f 0.1247577f               // d2=1
#define WS2f 0.0571180f               // d2=2

__global__ __launch_bounds__(256, 3) void bilateral8(
    const float* __restrict__ depth,   // [N,1,H,W]
    const float* __restrict__ color,   // [N,3,H,W]
    const float* __restrict__ mask,    // [N,1,H,W]
    float* __restrict__ out)           // [N,3,H,W]
{
    // XCD-aware swizzle: 1024 blocks, nwg%8==0 -> bijective; each XCD gets
    // 128 contiguous logical blocks = 512 contiguous rows (L2 row reuse).
    const int b = blockIdx.x;
    const int logical = (b & 7) * 128 + (b >> 3);
    const int tid = logical * 256 + (int)threadIdx.x;
    const int lane = threadIdx.x & 63;
    const int wv = tid >> 6;                  // global wave id == (n,h)
    const int h = wv & (HH - 1);
    const int n = wv >> 9;
    const int w0 = lane << 3;                 // 8 px per lane

    const float* dptr = depth + (size_t)n * HW;
    const float* mptr = mask  + (size_t)n * HW;
    const float* c0p  = color + (size_t)n * 3 * HW;
    const float* c1p  = c0p + HW;
    const float* c2p  = c0p + 2 * HW;

    // 10-wide window rows: [w0-1 .. w0+8]
    float D1[10], M1[10], A1[10], B1[10], C1[10];   // center row
    float Dr[10], Mr[10], Ar[10], Br[10], Cr[10];   // streamed row (h-1 then h+1)

#define LOADROW(dst, base, ro) do {                                          \
    const float4 _a = *reinterpret_cast<const float4*>((base) + (ro));       \
    const float4 _b = *reinterpret_cast<const float4*>((base) + (ro) + 4);   \
    const float _l = __shfl_up(_b.w, 1);                                     \
    const float _r = __shfl_down(_a.x, 1);                                   \
    dst[0] = (lane == 0)  ? 0.0f : _l;                                       \
    dst[9] = (lane == 63) ? 0.0f : _r;                                       \
    dst[1] = _a.x; dst[2] = _a.y; dst[3] = _a.z; dst[4] = _a.w;              \
    dst[5] = _b.x; dst[6] = _b.y; dst[7] = _b.z; dst[8] = _b.w;              \
} while (0)

#define ZEROROW(dst) do {                                                    \
    _Pragma("unroll") for (int _i = 0; _i < 10; ++_i) dst[_i] = 0.0f;        \
} while (0)

    const int ro1 = h * WW + w0;

    // Phase 0: issue center-row loads, then row h-1 loads (latency hidden
    // under phase-A compute).
    LOADROW(D1, dptr, ro1);
    LOADROW(M1, mptr, ro1);
    LOADROW(A1, c0p,  ro1);
    LOADROW(B1, c1p,  ro1);
    LOADROW(C1, c2p,  ro1);

    if (h > 0) {
        const int ro = ro1 - WW;
        LOADROW(Dr, dptr, ro);
        LOADROW(Mr, mptr, ro);
        LOADROW(Ar, c0p,  ro);
        LOADROW(Br, c1p,  ro);
        LOADROW(Cr, c2p,  ro);
    } else {
        ZEROROW(Dr); ZEROROW(Mr); ZEROROW(Ar); ZEROROW(Br); ZEROROW(Cr);
    }

    float Swd[8], Swc[8], St[8], S0[8], S1[8], S2[8];

    // Phase A: center row. 9 unique horizontal pair weights (symmetric).
    float pwd[9], pwc[9];
    #pragma unroll
    for (int j = 0; j < 9; ++j) {
        const float dd = D1[j] - D1[j + 1];
        pwd[j] = E2(KEXP * dd * dd);
        const float f0 = A1[j] - A1[j + 1];
        const float f1 = B1[j] - B1[j + 1];
        const float f2 = C1[j] - C1[j + 1];
        pwc[j] = E2(KEXP * f0 * f0) + E2(KEXP * f1 * f1) + E2(KEXP * f2 * f2);
    }

    #pragma unroll
    for (int i = 0; i < 8; ++i) {
        const int ci = i + 1;
        // center tap: wd = 1, wc = 3 (all deltas zero)
        float t = (3.0f * WS0f) * M1[ci];
        Swd[i] = 1.0f; Swc[i] = 3.0f; St[i] = t;
        S0[i] = t * A1[ci]; S1[i] = t * B1[ci]; S2[i] = t * C1[ci];
        // left tap (window col i) -> pair i
        float g = pwd[i] * pwc[i];
        t = g * WS1f * M1[i];
        Swd[i] += pwd[i]; Swc[i] += pwc[i]; St[i] += t;
        S0[i] += t * A1[i]; S1[i] += t * B1[i]; S2[i] += t * C1[i];
        // right tap (window col i+2) -> pair i+1
        g = pwd[i + 1] * pwc[i + 1];
        t = g * WS1f * M1[i + 2];
        Swd[i] += pwd[i + 1]; Swc[i] += pwc[i + 1]; St[i] += t;
        S0[i] += t * A1[i + 2]; S1[i] += t * B1[i + 2]; S2[i] += t * C1[i + 2];
    }

#define COMPROW() do {                                                       \
    _Pragma("unroll")                                                        \
    for (int i = 0; i < 8; ++i) {                                            \
        const float dc  = D1[i + 1];                                         \
        const float cc0 = A1[i + 1];                                         \
        const float cc1 = B1[i + 1];                                         \
        const float cc2 = C1[i + 1];                                         \
        _Pragma("unroll")                                                    \
        for (int dj = 0; dj < 3; ++dj) {                                     \
            const int c = i + dj;                                            \
            const float dd = Dr[c] - dc;                                     \
            const float wd = E2(KEXP * dd * dd);                             \
            const float f0 = Ar[c] - cc0;                                    \
            const float f1 = Br[c] - cc1;                                    \
            const float f2 = Cr[c] - cc2;                                    \
            const float wc = E2(KEXP * f0 * f0) + E2(KEXP * f1 * f1)         \
                           + E2(KEXP * f2 * f2);                             \
            const float ws = (dj == 1) ? WS1f : WS2f;                        \
            const float t = wd * wc * ws * Mr[c];                            \
            Swd[i] += wd; Swc[i] += wc; St[i] += t;                          \
            S0[i] += t * Ar[c]; S1[i] += t * Br[c]; S2[i] += t * Cr[c];      \
        }                                                                    \
    }                                                                        \
} while (0)

    // Phase B: row h-1
    COMPROW();

    // Phase C: row h+1
    if (h < HH - 1) {
        const int ro = ro1 + WW;
        LOADROW(Dr, dptr, ro);
        LOADROW(Mr, mptr, ro);
        LOADROW(Ar, c0p,  ro);
        LOADROW(Br, c1p,  ro);
        LOADROW(Cr, c2p,  ro);
    } else {
        ZEROROW(Dr); ZEROROW(Mr); ZEROROW(Ar); ZEROROW(Br); ZEROROW(Cr);
    }
    COMPROW();

    // Epilogue: out = Stc / (St + 9e-7 * Swd * Swc)
    float o0[8], o1[8], o2[8];
    #pragma unroll
    for (int i = 0; i < 8; ++i) {
        const float sn = Swd[i] * Swc[i];
        const float denom = St[i] + 9e-7f * sn;
        const float inv = __builtin_amdgcn_rcpf(denom);
        o0[i] = S0[i] * inv; o1[i] = S1[i] * inv; o2[i] = S2[i] * inv;
    }

    float* po = out + (size_t)n * 3 * HW + ro1;
    *reinterpret_cast<float4*>(po)              = make_float4(o0[0], o0[1], o0[2], o0[3]);
    *reinterpret_cast<float4*>(po + 4)          = make_float4(o0[4], o0[5], o0[6], o0[7]);
    *reinterpret_cast<float4*>(po + HW)         = make_float4(o1[0], o1[1], o1[2], o1[3]);
    *reinterpret_cast<float4*>(po + HW + 4)     = make_float4(o1[4], o1[5], o1[6], o1[7]);
    *reinterpret_cast<float4*>(po + 2 * HW)     = make_float4(o2[0], o2[1], o2[2], o2[3]);
    *reinterpret_cast<float4*>(po + 2 * HW + 4) = make_float4(o2[4], o2[5], o2[6], o2[7]);
}

extern "C" void kernel_launch(void* const* d_in, const int* in_sizes, int n_in,
                              void* d_out, int out_size, void* d_ws, size_t ws_size,
                              hipStream_t stream) {
    const float* depth = (const float*)d_in[0];
    const float* color = (const float*)d_in[1];
    const float* mask  = (const float*)d_in[2];
    float* out = (float*)d_out;

    // 8 images * 512 rows = 4096 waves; 4 waves/block -> 1024 blocks
    bilateral8<<<1024, 256, 0, stream>>>(depth, color, mask, out);
}

// Round 4
// 63.053 us; speedup vs baseline: 1.0965x; 1.0965x over previous
//
#include <hip/hip_runtime.h>

// BilateralFilter fp32, 8 images 512x512, 3x3, sigma=0.8.
// Thread tile: 2 rows x 4 cols (one float4 wide). Wave = 2 rows x 256 cols.
// Pair-weight symmetry: each unique neighbor pair's (wd,wc) computed ONCE
// and accumulated into both endpoint pixels. Edges via __shfl + 2-lane
// predicated scalar loads. All global accesses 16B-contiguous per lane.

constexpr int HH = 512;
constexpr int WW = 512;
constexpr int HW = HH * WW;

#define KEXP (-1.1271055f)            // -(1/(2*0.8^2)) * log2(e)
#define E2(x) __builtin_amdgcn_exp2f(x)
#define WS0f 0.2724967f               // normalized spatial gaussian, d2=0
#define WS1f 0.1247577f               // d2=1
#define WS2f 0.0571180f               // d2=2

__global__ __launch_bounds__(256, 3) void bilateral_pair(
    const float* __restrict__ depth,   // [N,1,H,W]
    const float* __restrict__ color,   // [N,3,H,W]
    const float* __restrict__ mask,    // [N,1,H,W]
    float* __restrict__ out)           // [N,3,H,W]
{
    const int lane = threadIdx.x & 63;
    const int wg   = blockIdx.x * 4 + (threadIdx.x >> 6);
    const int n    = wg >> 9;               // image 0..7
    const int rem  = wg & 511;
    const int hp   = rem >> 1;              // row-pair 0..255
    const int half = rem & 1;               // which 256-col half
    const int r0   = hp * 2;
    const int c0   = half * 256 + lane * 4;

    const float* dptr = depth + (size_t)n * HW;
    const float* mptr = mask  + (size_t)n * HW;
    const float* c0p  = color + (size_t)n * 3 * HW;
    const float* c1p  = c0p + HW;
    const float* c2p  = c0p + 2 * HW;

    // Row data: [plane][windowcol]; planes 0=D 1=M 2=A 3=B 4=C; cols w-1..w+4
    float P[5][6], Cc[5][6], Nn[5][6];

#define SPREAD(dst, q, e) do {                                               \
    const float _l = __shfl_up((q).w, 1);                                    \
    const float _r = __shfl_down((q).x, 1);                                  \
    dst[0] = (lane == 0)  ? (e) : _l;                                        \
    dst[5] = (lane == 63) ? (e) : _r;                                        \
    dst[1] = (q).x; dst[2] = (q).y; dst[3] = (q).z; dst[4] = (q).w;          \
} while (0)

#define LOADROW(dst, r) do {                                                 \
    if ((unsigned)(r) < (unsigned)HH) {  /* wave-uniform */                  \
        const int ro = (r) * WW + c0;                                        \
        const float4 qd = *reinterpret_cast<const float4*>(dptr + ro);       \
        const float4 qm = *reinterpret_cast<const float4*>(mptr + ro);       \
        const float4 qa = *reinterpret_cast<const float4*>(c0p + ro);        \
        const float4 qb = *reinterpret_cast<const float4*>(c1p + ro);        \
        const float4 qc = *reinterpret_cast<const float4*>(c2p + ro);        \
        float ed = 0.f, em = 0.f, ea = 0.f, eb = 0.f, ec = 0.f;              \
        const int eo = (lane == 0) ? ro - 1 : ro + 4;                        \
        const bool ev = (lane == 0) ? (half == 1)                            \
                                    : ((lane == 63) && (half == 0));         \
        if (ev) {                                                            \
            ed = dptr[eo]; em = mptr[eo];                                    \
            ea = c0p[eo];  eb = c1p[eo]; ec = c2p[eo];                       \
        }                                                                    \
        SPREAD(dst[0], qd, ed); SPREAD(dst[1], qm, em);                      \
        SPREAD(dst[2], qa, ea); SPREAD(dst[3], qb, eb);                      \
        SPREAD(dst[4], qc, ec);                                              \
    } else {                                                                 \
        _Pragma("unroll") for (int _p = 0; _p < 5; ++_p)                     \
        _Pragma("unroll") for (int _j = 0; _j < 6; ++_j) dst[_p][_j] = 0.f;  \
    }                                                                        \
} while (0)

    // Accumulators for the two output rows (prefix a = r0, b = r0+1)
    float aSwd[4], aSwc[4], aSt[4], aS0[4], aS1[4], aS2[4];
    float bSwd[4], bSwc[4], bSt[4], bS0[4], bS1[4], bS2[4];
    #pragma unroll
    for (int i = 0; i < 4; ++i) {
        aSwd[i]=0.f; aSwc[i]=0.f; aSt[i]=0.f; aS0[i]=0.f; aS1[i]=0.f; aS2[i]=0.f;
        bSwd[i]=0.f; bSwc[i]=0.f; bSt[i]=0.f; bS0[i]=0.f; bS1[i]=0.f; bS2[i]=0.f;
    }

// Pairs between row Pd (upper) and row Qd (lower); doP: accumulate S-taps of
// Pd's pixels; doQ: accumulate N-taps of Qd's pixels. Each pair computed once.
#define GAP(Pd, Qd, accP, accQ, doP, doQ) do {                               \
    _Pragma("unroll") for (int a = 0; a < 6; ++a) {                          \
    _Pragma("unroll") for (int db = -1; db <= 1; ++db) {                     \
        const int bb = a + db;                                               \
        if (bb < 0 || bb > 5) continue;                                      \
        const bool useP = (doP) && (a >= 1 && a <= 4);                       \
        const bool useQ = (doQ) && (bb >= 1 && bb <= 4);                     \
        if (!useP && !useQ) continue;                                        \
        const float dd = Pd[0][a] - Qd[0][bb];                               \
        const float pwd = E2(KEXP * dd * dd);                                \
        const float f0 = Pd[2][a] - Qd[2][bb];                               \
        const float f1 = Pd[3][a] - Qd[3][bb];                               \
        const float f2 = Pd[4][a] - Qd[4][bb];                               \
        const float pwc = E2(KEXP * f0 * f0) + E2(KEXP * f1 * f1)            \
                        + E2(KEXP * f2 * f2);                                \
        const float g = pwd * pwc;                                           \
        const float ws = (db == 0) ? WS1f : WS2f;                            \
        if (useP) { const int i = a - 1;                                     \
            const float t = g * ws * Qd[1][bb];                              \
            accP##Swd[i] += pwd; accP##Swc[i] += pwc; accP##St[i] += t;      \
            accP##S0[i] += t * Qd[2][bb];                                    \
            accP##S1[i] += t * Qd[3][bb];                                    \
            accP##S2[i] += t * Qd[4][bb]; }                                  \
        if (useQ) { const int i = bb - 1;                                    \
            const float t = g * ws * Pd[1][a];                               \
            accQ##Swd[i] += pwd; accQ##Swc[i] += pwc; accQ##St[i] += t;      \
            accQ##S0[i] += t * Pd[2][a];                                     \
            accQ##S1[i] += t * Pd[3][a];                                     \
            accQ##S2[i] += t * Pd[4][a]; }                                   \
    } }                                                                      \
} while (0)

// Horizontal pairs + center tap within a row.
#define HROW(Rd, acc) do {                                                   \
    float hwd[5], hwc[5];                                                    \
    _Pragma("unroll") for (int j = 0; j < 5; ++j) {                          \
        const float dd = Rd[0][j] - Rd[0][j + 1];                            \
        hwd[j] = E2(KEXP * dd * dd);                                         \
        const float f0 = Rd[2][j] - Rd[2][j + 1];                            \
        const float f1 = Rd[3][j] - Rd[3][j + 1];                            \
        const float f2 = Rd[4][j] - Rd[4][j + 1];                            \
        hwc[j] = E2(KEXP * f0 * f0) + E2(KEXP * f1 * f1)                     \
               + E2(KEXP * f2 * f2);                                         \
    }                                                                        \
    _Pragma("unroll") for (int i = 0; i < 4; ++i) {                          \
        const int ci = i + 1;                                                \
        { const float t = (3.0f * WS0f) * Rd[1][ci];   /* center: wd=1,wc=3 */\
          acc##Swd[i] += 1.0f; acc##Swc[i] += 3.0f; acc##St[i] += t;         \
          acc##S0[i] += t * Rd[2][ci]; acc##S1[i] += t * Rd[3][ci];          \
          acc##S2[i] += t * Rd[4][ci]; }                                     \
        { const float t = hwd[i] * hwc[i] * WS1f * Rd[1][i];   /* west */    \
          acc##Swd[i] += hwd[i]; acc##Swc[i] += hwc[i]; acc##St[i] += t;     \
          acc##S0[i] += t * Rd[2][i]; acc##S1[i] += t * Rd[3][i];            \
          acc##S2[i] += t * Rd[4][i]; }                                      \
        { const float t = hwd[i+1] * hwc[i+1] * WS1f * Rd[1][i+2]; /* east */\
          acc##Swd[i] += hwd[i+1]; acc##Swc[i] += hwc[i+1]; acc##St[i] += t; \
          acc##S0[i] += t * Rd[2][i+2]; acc##S1[i] += t * Rd[3][i+2];        \
          acc##S2[i] += t * Rd[4][i+2]; }                                    \
    }                                                                        \
} while (0)

    LOADROW(P,  r0 - 1);
    LOADROW(Cc, r0);
    LOADROW(Nn, r0 + 1);

    GAP(P, Cc, a, a, false, true);      // N-taps of row r0 (P data consumed)
    LOADROW(P, r0 + 2);                 // reuse P's registers for row r0+2
    HROW(Cc, a);                        // center + E/W of row r0
    GAP(Cc, Nn, a, b, true, true);      // S-taps of r0 + N-taps of r0+1
    HROW(Nn, b);                        // center + E/W of row r0+1
    GAP(Nn, P, b, b, true, false);      // S-taps of row r0+1

    // out = Stc / (St + 9e-7 * Swd * Swc)
    float oa0[4], oa1[4], oa2[4], ob0[4], ob1[4], ob2[4];
    #pragma unroll
    for (int i = 0; i < 4; ++i) {
        const float invA = __builtin_amdgcn_rcpf(aSt[i] + 9e-7f * aSwd[i] * aSwc[i]);
        oa0[i] = aS0[i] * invA; oa1[i] = aS1[i] * invA; oa2[i] = aS2[i] * invA;
        const float invB = __builtin_amdgcn_rcpf(bSt[i] + 9e-7f * bSwd[i] * bSwc[i]);
        ob0[i] = bS0[i] * invB; ob1[i] = bS1[i] * invB; ob2[i] = bS2[i] * invB;
    }

    float* po = out + (size_t)n * 3 * HW + r0 * WW + c0;
    *reinterpret_cast<float4*>(po)               = make_float4(oa0[0], oa0[1], oa0[2], oa0[3]);
    *reinterpret_cast<float4*>(po + HW)          = make_float4(oa1[0], oa1[1], oa1[2], oa1[3]);
    *reinterpret_cast<float4*>(po + 2 * HW)      = make_float4(oa2[0], oa2[1], oa2[2], oa2[3]);
    *reinterpret_cast<float4*>(po + WW)          = make_float4(ob0[0], ob0[1], ob0[2], ob0[3]);
    *reinterpret_cast<float4*>(po + WW + HW)     = make_float4(ob1[0], ob1[1], ob1[2], ob1[3]);
    *reinterpret_cast<float4*>(po + WW + 2 * HW) = make_float4(ob2[0], ob2[1], ob2[2], ob2[3]);
}

extern "C" void kernel_launch(void* const* d_in, const int* in_sizes, int n_in,
                              void* d_out, int out_size, void* d_ws, size_t ws_size,
                              hipStream_t stream) {
    const float* depth = (const float*)d_in[0];
    const float* color = (const float*)d_in[1];
    const float* mask  = (const float*)d_in[2];
    float* out = (float*)d_out;

    // 8 images * 256 row-pairs * 2 halves = 4096 waves; 4 waves/block
    bilateral_pair<<<1024, 256, 0, stream>>>(depth, color, mask, out);
}

// Round 5
// 26.147 us; speedup vs baseline: 2.6443x; 2.4115x over previous
//
#include <hip/hip_runtime.h>

// BilateralFilter fp32, 8 images 512x512, 3x3, sigma=0.8.
// Thread tile: 2 rows x 4 cols. Wave = 2 rows x 256 cols (half-row pair).
// Pair-weight symmetry inside the tile (H pairs within each row, V/diag pairs
// between the two rows computed once, accumulated into both endpoints).
// NO __shfl (edges via predicated scalar loads), NO min-occupancy hint,
// streamed row windows -> peak ~150 VGPR, no scratch.

constexpr int HH = 512;
constexpr int WW = 512;
constexpr int HW = HH * WW;

#define KEXP (-1.1271055f)            // -(1/(2*0.8^2)) * log2(e)
#define E2(x) __builtin_amdgcn_exp2f(x)
#define WS0f 0.2724967f               // normalized spatial gaussian, d2=0
#define WS1f 0.1247577f               // d2=1
#define WS2f 0.0571180f               // d2=2

__global__ __launch_bounds__(256) void bilateral_v5(
    const float* __restrict__ depth,   // [N,1,H,W]
    const float* __restrict__ color,   // [N,3,H,W]
    const float* __restrict__ mask,    // [N,1,H,W]
    float* __restrict__ out)           // [N,3,H,W]
{
    const int lane = threadIdx.x & 63;
    const int wg   = blockIdx.x * 4 + (threadIdx.x >> 6);
    const int n    = wg >> 9;               // image 0..7
    const int rem  = wg & 511;
    const int hp   = rem >> 1;              // row-pair 0..255
    const int half = rem & 1;               // column half
    const int rA   = hp * 2;
    const int c0   = half * 256 + lane * 4;

    const float* dptr = depth + (size_t)n * HW;
    const float* mptr = mask  + (size_t)n * HW;
    const float* xptr = color + (size_t)n * 3 * HW;
    const float* yptr = xptr + HW;
    const float* zptr = xptr + 2 * HW;

    const bool hasL = (c0 > 0);
    const bool hasR = (c0 < WW - 4);

    // Window rows: cols 0..5 = w-1 .. w+4. Planes: D depth, M mask, X/Y/Z color.
    float AD[6], AM[6], AX[6], AY[6], AZ[6];
    float BD[6], BM[6], BX[6], BY[6], BZ[6];

#define LOADP(W, base, ro) do {                                              \
    const float4 _q = *reinterpret_cast<const float4*>((base) + (ro));       \
    W[1] = _q.x; W[2] = _q.y; W[3] = _q.z; W[4] = _q.w;                      \
    W[0] = hasL ? (base)[(ro) - 1] : 0.0f;                                   \
    W[5] = hasR ? (base)[(ro) + 4] : 0.0f;                                   \
} while (0)

#define LOADW(D_, M_, X_, Y_, Z_, r) do {                                    \
    const int _ro = (r) * WW + c0;                                           \
    LOADP(D_, dptr, _ro); LOADP(M_, mptr, _ro);                              \
    LOADP(X_, xptr, _ro); LOADP(Y_, yptr, _ro); LOADP(Z_, zptr, _ro);        \
} while (0)

    // Accumulators (a = row rA, b = row rA+1)
    float aSwd[4], aSwc[4], aSt[4], aS0[4], aS1[4], aS2[4];
    float bSwd[4], bSwc[4], bSt[4], bS0[4], bS1[4], bS2[4];
    #pragma unroll
    for (int i = 0; i < 4; ++i) {
        aSwd[i]=0.f; aSwc[i]=0.f; aSt[i]=0.f; aS0[i]=0.f; aS1[i]=0.f; aS2[i]=0.f;
        bSwd[i]=0.f; bSwc[i]=0.f; bSt[i]=0.f; bS0[i]=0.f; bS1[i]=0.f; bS2[i]=0.f;
    }

// Horizontal pass within one row: center tap + shared E/W pair weights.
#define HPASS(D_, M_, X_, Y_, Z_, Swd, Swc, St, S0, S1, S2) do {             \
    float hwd[5], hwc[5];                                                    \
    _Pragma("unroll") for (int j = 0; j < 5; ++j) {                          \
        const float dd = D_[j] - D_[j + 1];                                  \
        hwd[j] = E2(KEXP * dd * dd);                                         \
        const float f0 = X_[j] - X_[j + 1];                                  \
        const float f1 = Y_[j] - Y_[j + 1];                                  \
        const float f2 = Z_[j] - Z_[j + 1];                                  \
        hwc[j] = E2(KEXP * f0 * f0) + E2(KEXP * f1 * f1)                     \
               + E2(KEXP * f2 * f2);                                         \
    }                                                                        \
    _Pragma("unroll") for (int i = 0; i < 4; ++i) {                          \
        const int ci = i + 1;                                                \
        { const float t = (3.0f * WS0f) * M_[ci];     /* center wd=1 wc=3 */ \
          Swd[i] += 1.0f; Swc[i] += 3.0f; St[i] += t;                        \
          S0[i] += t * X_[ci]; S1[i] += t * Y_[ci]; S2[i] += t * Z_[ci]; }   \
        { const float t = hwd[i] * hwc[i] * WS1f * M_[i];        /* west */  \
          Swd[i] += hwd[i]; Swc[i] += hwc[i]; St[i] += t;                    \
          S0[i] += t * X_[i]; S1[i] += t * Y_[i]; S2[i] += t * Z_[i]; }      \
        { const float t = hwd[i+1] * hwc[i+1] * WS1f * M_[i+2];  /* east */  \
          Swd[i] += hwd[i+1]; Swc[i] += hwc[i+1]; St[i] += t;                \
          S0[i] += t * X_[i+2]; S1[i] += t * Y_[i+2]; S2[i] += t * Z_[i+2];} \
    }                                                                        \
} while (0)

    LOADW(AD, AM, AX, AY, AZ, rA);
    LOADW(BD, BM, BX, BY, BZ, rA + 1);

    // Save row centers before window registers are reused for side rows.
    float cdA[4], cxA[4], cyA[4], czA[4];
    float cdB[4], cxB[4], cyB[4], czB[4];
    #pragma unroll
    for (int i = 0; i < 4; ++i) {
        cdA[i] = AD[i+1]; cxA[i] = AX[i+1]; cyA[i] = AY[i+1]; czA[i] = AZ[i+1];
        cdB[i] = BD[i+1]; cxB[i] = BX[i+1]; cyB[i] = BY[i+1]; czB[i] = BZ[i+1];
    }

    HPASS(AD, AM, AX, AY, AZ, aSwd, aSwc, aSt, aS0, aS1, aS2);
    HPASS(BD, BM, BX, BY, BZ, bSwd, bSwc, bSt, bS0, bS1, bS2);

    // Vertical + diagonal pairs between rows A and B: computed once,
    // accumulated into both interior endpoints.
    #pragma unroll
    for (int a = 0; a < 6; ++a) {
        #pragma unroll
        for (int db = -1; db <= 1; ++db) {
            const int bb = a + db;
            if (bb < 0 || bb > 5) continue;
            const bool useA = (a >= 1 && a <= 4);
            const bool useB = (bb >= 1 && bb <= 4);
            if (!useA && !useB) continue;
            const float dd = AD[a] - BD[bb];
            const float pwd = E2(KEXP * dd * dd);
            const float f0 = AX[a] - BX[bb];
            const float f1 = AY[a] - BY[bb];
            const float f2 = AZ[a] - BZ[bb];
            const float pwc = E2(KEXP * f0 * f0) + E2(KEXP * f1 * f1)
                            + E2(KEXP * f2 * f2);
            const float g = pwd * pwc;
            const float ws = (db == 0) ? WS1f : WS2f;
            if (useA) {
                const int i = a - 1;
                const float t = g * ws * BM[bb];
                aSwd[i] += pwd; aSwc[i] += pwc; aSt[i] += t;
                aS0[i] += t * BX[bb]; aS1[i] += t * BY[bb]; aS2[i] += t * BZ[bb];
            }
            if (useB) {
                const int i = bb - 1;
                const float t = g * ws * AM[a];
                bSwd[i] += pwd; bSwc[i] += pwc; bSt[i] += t;
                bS0[i] += t * AX[a]; bS1[i] += t * AY[a]; bS2[i] += t * AZ[a];
            }
        }
    }

// One-sided pass: side-row window T vs saved centers of target row.
#define SIDE(TD, TM, TX, TY, TZ, cd, cx, cy, cz, Swd, Swc, St, S0, S1, S2) do { \
    _Pragma("unroll") for (int i = 0; i < 4; ++i) {                          \
        _Pragma("unroll") for (int dj = 0; dj < 3; ++dj) {                   \
            const int c = i + dj;                                            \
            const float dd = TD[c] - cd[i];                                  \
            const float wd = E2(KEXP * dd * dd);                             \
            const float f0 = TX[c] - cx[i];                                  \
            const float f1 = TY[c] - cy[i];                                  \
            const float f2 = TZ[c] - cz[i];                                  \
            const float wc = E2(KEXP * f0 * f0) + E2(KEXP * f1 * f1)         \
                           + E2(KEXP * f2 * f2);                             \
            const float ws = (dj == 1) ? WS1f : WS2f;                        \
            const float t = wd * wc * ws * TM[c];                            \
            Swd[i] += wd; Swc[i] += wc; St[i] += t;                          \
            S0[i] += t * TX[c]; S1[i] += t * TY[c]; S2[i] += t * TZ[c];      \
        }                                                                    \
    }                                                                        \
} while (0)

    if (hp > 0) {               // wave-uniform: row above exists
        LOADW(AD, AM, AX, AY, AZ, rA - 1);
        SIDE(AD, AM, AX, AY, AZ, cdA, cxA, cyA, czA,
             aSwd, aSwc, aSt, aS0, aS1, aS2);
    }
    if (hp < 255) {             // wave-uniform: row below exists
        LOADW(BD, BM, BX, BY, BZ, rA + 2);
        SIDE(BD, BM, BX, BY, BZ, cdB, cxB, cyB, czB,
             bSwd, bSwc, bSt, bS0, bS1, bS2);
    }
    // (skipped side passes at image top/bottom only omit the ~9e-7*Swd*Swc
    //  zero-pad contribution -> error << 1e-3, far under threshold)

    // out = Stc / (St + 9e-7 * Swd * Swc)
    float oa0[4], oa1[4], oa2[4], ob0[4], ob1[4], ob2[4];
    #pragma unroll
    for (int i = 0; i < 4; ++i) {
        const float invA = __builtin_amdgcn_rcpf(aSt[i] + 9e-7f * aSwd[i] * aSwc[i]);
        oa0[i] = aS0[i] * invA; oa1[i] = aS1[i] * invA; oa2[i] = aS2[i] * invA;
        const float invB = __builtin_amdgcn_rcpf(bSt[i] + 9e-7f * bSwd[i] * bSwc[i]);
        ob0[i] = bS0[i] * invB; ob1[i] = bS1[i] * invB; ob2[i] = bS2[i] * invB;
    }

    float* po = out + (size_t)n * 3 * HW + rA * WW + c0;
    *reinterpret_cast<float4*>(po)               = make_float4(oa0[0], oa0[1], oa0[2], oa0[3]);
    *reinterpret_cast<float4*>(po + HW)          = make_float4(oa1[0], oa1[1], oa1[2], oa1[3]);
    *reinterpret_cast<float4*>(po + 2 * HW)      = make_float4(oa2[0], oa2[1], oa2[2], oa2[3]);
    *reinterpret_cast<float4*>(po + WW)          = make_float4(ob0[0], ob0[1], ob0[2], ob0[3]);
    *reinterpret_cast<float4*>(po + WW + HW)     = make_float4(ob1[0], ob1[1], ob1[2], ob1[3]);
    *reinterpret_cast<float4*>(po + WW + 2 * HW) = make_float4(ob2[0], ob2[1], ob2[2], ob2[3]);
}

extern "C" void kernel_launch(void* const* d_in, const int* in_sizes, int n_in,
                              void* d_out, int out_size, void* d_ws, size_t ws_size,
                              hipStream_t stream) {
    const float* depth = (const float*)d_in[0];
    const float* color = (const float*)d_in[1];
    const float* mask  = (const float*)d_in[2];
    float* out = (float*)d_out;

    // 8 images * 256 row-pairs * 2 halves = 4096 waves; 4 waves/block
    bilateral_v5<<<1024, 256, 0, stream>>>(depth, color, mask, out);
}